// Round 1
// baseline (1674.048 us; speedup 1.0000x reference)
//
#include <hip/hip_runtime.h>
#include <stdint.h>

#define MDIM 8192
#define NDIM 16384
#define KDIM 4096

typedef __attribute__((ext_vector_type(8))) short bf16x8;
typedef __attribute__((ext_vector_type(4))) float f32x4;

__device__ __forceinline__ unsigned short f2bf(float f) {
    unsigned int u = __float_as_uint(f);
    u += 0x7FFFu + ((u >> 16) & 1u);   // RNE; inputs are finite/normal
    return (unsigned short)(u >> 16);
}

__device__ __forceinline__ void gload_lds16(const void* g, void* l) {
    __builtin_amdgcn_global_load_lds(
        (const __attribute__((address_space(1))) void*)g,
        (__attribute__((address_space(3))) void*)l,
        16, 0, 0);
}

// ---------------- conversion kernels ----------------

__global__ __launch_bounds__(256)
void convert_x_kernel(const float* __restrict__ x, unsigned short* __restrict__ xb) {
    const long n8 = (long)MDIM * KDIM / 8;
    long i = (long)blockIdx.x * blockDim.x + threadIdx.x;
    const long stride = (long)gridDim.x * blockDim.x;
    for (; i < n8; i += stride) {
        const float4* p = (const float4*)(x + i * 8);
        float4 a = p[0];
        float4 b = p[1];
        union { unsigned short u[8]; uint4 v; } r;
        r.u[0] = f2bf(a.x); r.u[1] = f2bf(a.y); r.u[2] = f2bf(a.z); r.u[3] = f2bf(a.w);
        r.u[4] = f2bf(b.x); r.u[5] = f2bf(b.y); r.u[6] = f2bf(b.z); r.u[7] = f2bf(b.w);
        *(uint4*)(xb + i * 8) = r.v;
    }
}

__global__ __launch_bounds__(256)
void convert_w_kernel(const int* __restrict__ q, const int* __restrict__ zp,
                      unsigned short* __restrict__ wb) {
    const long n8 = (long)NDIM * KDIM / 8;
    long i = (long)blockIdx.x * blockDim.x + threadIdx.x;
    const long stride = (long)gridDim.x * blockDim.x;
    for (; i < n8; i += stride) {
        const long e = i * 8;
        const int o = (int)(e >> 12);          // KDIM = 4096; 8-groups never cross a row
        const int z = zp[o];
        const int4* p = (const int4*)(q + e);
        int4 a = p[0];
        int4 b = p[1];
        union { unsigned short u[8]; uint4 v; } r;
        r.u[0] = f2bf((float)(a.x - z)); r.u[1] = f2bf((float)(a.y - z));
        r.u[2] = f2bf((float)(a.z - z)); r.u[3] = f2bf((float)(a.w - z));
        r.u[4] = f2bf((float)(b.x - z)); r.u[5] = f2bf((float)(b.y - z));
        r.u[6] = f2bf((float)(b.z - z)); r.u[7] = f2bf((float)(b.w - z));
        *(uint4*)(wb + e) = r.v;
    }
}

// ---------------- main bf16 MFMA GEMM (m97 128^2 structure) ----------------
// C[m,n] = scale[n] * sum_k A[m,k] * W[n,k];  A:[M][K] bf16, W:[N][K] bf16 (B^T layout)

__global__ __launch_bounds__(256)
void gemm_kernel(const unsigned short* __restrict__ A,
                 const unsigned short* __restrict__ W,
                 const float* __restrict__ scale,
                 float* __restrict__ C) {
    __shared__ unsigned short lA[128 * 64];   // [128 rows][64 k] linear (global_load_lds dest)
    __shared__ unsigned short lB[128 * 64];

    // XCD-aware swizzle: nwg = 8192, divisible by 8 -> bijective
    const int nwg = (MDIM / 128) * (NDIM / 128);
    const int cpx = nwg / 8;
    const int wg  = (int)blockIdx.x;
    const int swz = (wg & 7) * cpx + (wg >> 3);
    const int ntn = NDIM / 128;               // 128
    const int bm  = swz / ntn;
    const int bn  = swz % ntn;

    const int tid  = threadIdx.x;
    const int wid  = tid >> 6;
    const int lane = tid & 63;
    const int wm   = wid >> 1;                // 2x2 wave grid, each wave 64x64
    const int wn   = wid & 1;

    f32x4 acc[4][4] = {};

    const long rowA = (long)bm * 128;
    const long rowB = (long)bn * 128;

    const int srow = lane >> 3;               // 0..7 row within 8-row chunk
    const int scol = (lane & 7) * 8;          // k element offset (16B)

    for (int k0 = 0; k0 < KDIM; k0 += 64) {
#pragma unroll
        for (int i = 0; i < 4; ++i) {
            const int chunk = wid * 4 + i;            // 0..15, 8 rows each
            const long r = (long)chunk * 8 + srow;    // 0..127
            gload_lds16(A + (rowA + r) * KDIM + k0 + scol, &lA[chunk * 512]);
            gload_lds16(W + (rowB + r) * KDIM + k0 + scol, &lB[chunk * 512]);
        }
        __syncthreads();   // compiler emits s_waitcnt vmcnt(0) lgkmcnt(0) before s_barrier

        const int klane = (lane >> 4) * 8;
#pragma unroll
        for (int kk = 0; kk < 64; kk += 32) {
            bf16x8 af[4], bfr[4];
#pragma unroll
            for (int i = 0; i < 4; ++i) {
                af[i]  = *(const bf16x8*)&lA[(wm * 64 + i * 16 + (lane & 15)) * 64 + kk + klane];
                bfr[i] = *(const bf16x8*)&lB[(wn * 64 + i * 16 + (lane & 15)) * 64 + kk + klane];
            }
#pragma unroll
            for (int i = 0; i < 4; ++i)
#pragma unroll
                for (int j = 0; j < 4; ++j)
                    acc[i][j] = __builtin_amdgcn_mfma_f32_16x16x32_bf16(af[i], bfr[j], acc[i][j], 0, 0, 0);
        }
        __syncthreads();
    }

    // Epilogue: D lane mapping (m89-verified): col = lane&15, row = (lane>>4)*4 + reg
#pragma unroll
    for (int j = 0; j < 4; ++j) {
        const int ncol = (int)rowB + wn * 64 + j * 16 + (lane & 15);
        const float s = scale[ncol];
#pragma unroll
        for (int i = 0; i < 4; ++i) {
            const long mrow = rowA + wm * 64 + i * 16 + (lane >> 4) * 4;
            float* cp = C + mrow * NDIM + ncol;
#pragma unroll
            for (int r = 0; r < 4; ++r)
                cp[(long)r * NDIM] = acc[i][j][r] * s;
        }
    }
}

// ---------------- safety fallback (no workspace needed, fp32, slow) ----------------

__global__ __launch_bounds__(256)
void fallback_kernel(const float* __restrict__ x, const int* __restrict__ q,
                     const float* __restrict__ scale, const int* __restrict__ zp,
                     float* __restrict__ out) {
    __shared__ float sA[64][17];
    __shared__ float sB[64][17];
    const int bn = (int)blockIdx.x % (NDIM / 64);
    const int bm = (int)blockIdx.x / (NDIM / 64);
    const int t  = threadIdx.x;
    const int tx = t & 15, ty = t >> 4;
    const long rowA = (long)bm * 64, rowB = (long)bn * 64;
    float acc[4][4] = {};
    for (int k0 = 0; k0 < KDIM; k0 += 16) {
#pragma unroll
        for (int i = 0; i < 4; ++i) {
            const int e = t + i * 256;
            const int r = e >> 4, c = e & 15;
            sA[r][c] = x[(rowA + r) * KDIM + k0 + c];
            const int o = (int)rowB + r;
            sB[r][c] = (float)(q[(long)o * KDIM + k0 + c] - zp[o]) * scale[o];
        }
        __syncthreads();
#pragma unroll
        for (int kk = 0; kk < 16; ++kk) {
            float a[4], b[4];
#pragma unroll
            for (int i = 0; i < 4; ++i) a[i] = sA[ty * 4 + i][kk];
#pragma unroll
            for (int j = 0; j < 4; ++j) b[j] = sB[tx * 4 + j][kk];
#pragma unroll
            for (int i = 0; i < 4; ++i)
#pragma unroll
                for (int j = 0; j < 4; ++j) acc[i][j] += a[i] * b[j];
        }
        __syncthreads();
    }
#pragma unroll
    for (int i = 0; i < 4; ++i) {
        const long r = rowA + ty * 4 + i;
#pragma unroll
        for (int j = 0; j < 4; ++j)
            out[r * NDIM + rowB + tx * 4 + j] = acc[i][j];
    }
}

// ---------------- launch ----------------

extern "C" void kernel_launch(void* const* d_in, const int* in_sizes, int n_in,
                              void* d_out, int out_size, void* d_ws, size_t ws_size,
                              hipStream_t stream) {
    const float* x     = (const float*)d_in[0];
    const int*   qw    = (const int*)d_in[1];
    const float* scale = (const float*)d_in[2];
    const int*   zp    = (const int*)d_in[3];
    float*       out   = (float*)d_out;

    const size_t needA = (size_t)MDIM * KDIM * sizeof(unsigned short);  // 64 MiB
    const size_t needW = (size_t)NDIM * KDIM * sizeof(unsigned short);  // 128 MiB

    if (ws_size >= needA + needW) {
        unsigned short* xb = (unsigned short*)d_ws;
        unsigned short* wb = xb + (size_t)MDIM * KDIM;
        convert_x_kernel<<<2048, 256, 0, stream>>>(x, xb);
        convert_w_kernel<<<4096, 256, 0, stream>>>(qw, zp, wb);
        gemm_kernel<<<(MDIM / 128) * (NDIM / 128), 256, 0, stream>>>(xb, wb, scale, out);
    } else {
        fallback_kernel<<<(MDIM / 64) * (NDIM / 64), 256, 0, stream>>>(x, qw, scale, zp, out);
    }
}

// Round 2
// 1265.548 us; speedup vs baseline: 1.3228x; 1.3228x over previous
//
#include <hip/hip_runtime.h>
#include <stdint.h>

#define MDIM 8192
#define NDIM 16384
#define KDIM 4096
#define NT   64          // K-tiles of BK=64

typedef __attribute__((ext_vector_type(8))) short bf16x8;
typedef __attribute__((ext_vector_type(4))) float f32x4;

__device__ __forceinline__ unsigned short f2bf(float f) {
    unsigned int u = __float_as_uint(f);
    u += 0x7FFFu + ((u >> 16) & 1u);   // RNE; inputs finite/normal
    return (unsigned short)(u >> 16);
}

__device__ __forceinline__ void gload_lds16(const void* g, void* l) {
    __builtin_amdgcn_global_load_lds(
        (const __attribute__((address_space(1))) void*)g,
        (__attribute__((address_space(3))) void*)l,
        16, 0, 0);
}

__device__ __forceinline__ f32x4 MFMA(bf16x8 a, bf16x8 b, f32x4 c) {
    return __builtin_amdgcn_mfma_f32_16x16x32_bf16(a, b, c, 0, 0, 0);
}

// ---------------- conversion kernels ----------------

__global__ __launch_bounds__(256)
void convert_x_kernel(const float* __restrict__ x, unsigned short* __restrict__ xb) {
    const long n8 = (long)MDIM * KDIM / 8;
    long i = (long)blockIdx.x * blockDim.x + threadIdx.x;
    const long stride = (long)gridDim.x * blockDim.x;
    for (; i < n8; i += stride) {
        const float4* p = (const float4*)(x + i * 8);
        float4 a = p[0];
        float4 b = p[1];
        union { unsigned short u[8]; uint4 v; } r;
        r.u[0] = f2bf(a.x); r.u[1] = f2bf(a.y); r.u[2] = f2bf(a.z); r.u[3] = f2bf(a.w);
        r.u[4] = f2bf(b.x); r.u[5] = f2bf(b.y); r.u[6] = f2bf(b.z); r.u[7] = f2bf(b.w);
        *(uint4*)(xb + i * 8) = r.v;
    }
}

__global__ __launch_bounds__(256)
void convert_w_kernel(const int* __restrict__ q, const int* __restrict__ zp,
                      unsigned short* __restrict__ wb) {
    const long n8 = (long)NDIM * KDIM / 8;
    long i = (long)blockIdx.x * blockDim.x + threadIdx.x;
    const long stride = (long)gridDim.x * blockDim.x;
    for (; i < n8; i += stride) {
        const long e = i * 8;
        const int o = (int)(e >> 12);          // KDIM = 4096
        const int z = zp[o];
        const int4* p = (const int4*)(q + e);
        int4 a = p[0];
        int4 b = p[1];
        union { unsigned short u[8]; uint4 v; } r;
        r.u[0] = f2bf((float)(a.x - z)); r.u[1] = f2bf((float)(a.y - z));
        r.u[2] = f2bf((float)(a.z - z)); r.u[3] = f2bf((float)(a.w - z));
        r.u[4] = f2bf((float)(b.x - z)); r.u[5] = f2bf((float)(b.y - z));
        r.u[6] = f2bf((float)(b.z - z)); r.u[7] = f2bf((float)(b.w - z));
        *(uint4*)(wb + e) = r.v;
    }
}

// ---------------- 256x256 8-wave 4-phase MFMA GEMM (T1+T2+T3+T4+T5) ----------------
// C[m,n] = scale[n] * sum_k A[m,k] * W[n,k]
// LDS: 2 bufs x 4 planes x 8192 halfwords = 128 KiB.
//   plane 0: A k-slice 0 (256 rows x 32 k)   plane 1: B k-slice 0
//   plane 2: A k-slice 1                     plane 3: B k-slice 1
// Within a plane, 16B chunk c of row r lives at slot r*4 + (c ^ ((r>>1)&3))
// (2-way bank conflicts = free). global_load_lds dest stays LINEAR; the
// inverse permutation is applied to the per-lane GLOBAL source address.
// Schedule per K-tile t (buf cur=t&1): 4 phases x 16 MFMA; phase p stages
// plane p-1 of K-tile t+1 into buf nxt. Counted waits vmcnt(4) at phase-2 and
// phase-4 ends (8 loads outstanding -> oldest K-tile's planes landed).

__global__ __launch_bounds__(512, 2)
void gemm8_kernel(const unsigned short* __restrict__ A,
                  const unsigned short* __restrict__ W,
                  const float* __restrict__ scale,
                  float* __restrict__ C) {
    extern __shared__ unsigned short lds[];   // 65536 halfwords

    const int wg  = (int)blockIdx.x;
    const int swz = (wg & 7) * 256 + (wg >> 3);   // 2048 wgs, %8==0 -> bijective
    const int bm  = swz >> 6;                      // 0..31
    const int bn  = swz & 63;                      // 0..63

    const int tid  = threadIdx.x;
    const int lane = tid & 63;
    const int wid  = tid >> 6;
    const int wm   = wid >> 2;        // 0..1  (128 rows each)
    const int wn   = wid & 3;         // 0..3  (64 cols each)
    const int l15  = lane & 15;
    const int c16  = lane >> 4;

    // swizzled read offset within a plane (halfwords): row*32 + chunk*8
    const int lro = l15 * 32 + ((c16 ^ ((l15 >> 1) & 3)) << 3);

    // staging: thread covers plane slots s0 = tid, s1 = 512+tid
    // slot s holds (row = s>>2, logical chunk c = (s&3) ^ ((s>>3)&3))
    const int s0 = tid, s1 = 512 + tid;
    const int soff0 = (s0 >> 2) * KDIM + (((s0 & 3) ^ ((s0 >> 3) & 3)) << 3);
    const int soff1 = (s1 >> 2) * KDIM + (((s1 & 3) ^ ((s1 >> 3) & 3)) << 3);
    const int d0 = s0 * 8, d1 = s1 * 8;   // halfword offsets in plane (16B/lane, linear)

    const unsigned short* Ab = A + (long)bm * 256 * KDIM;
    const unsigned short* Wb = W + (long)bn * 256 * KDIM;

#define STAGE(buf, p, base, kofs)                                                   \
    do {                                                                            \
        gload_lds16((base) + soff0 + (kofs), &lds[(buf) + (p) * 8192 + d0]);        \
        gload_lds16((base) + soff1 + (kofs), &lds[(buf) + (p) * 8192 + d1]);        \
    } while (0)

    f32x4 acc[8][4];
#pragma unroll
    for (int i = 0; i < 8; ++i)
#pragma unroll
        for (int j = 0; j < 4; ++j) acc[i][j] = (f32x4){0.f, 0.f, 0.f, 0.f};

    // prologue: K-tile 0 (8 loads); wait planes 0,1
    STAGE(0, 0, Ab, 0);
    STAGE(0, 1, Wb, 0);
    STAGE(0, 2, Ab, 32);
    STAGE(0, 3, Wb, 32);
    asm volatile("s_waitcnt vmcnt(4)" ::: "memory");
    __builtin_amdgcn_s_barrier();
    __builtin_amdgcn_sched_barrier(0);

    for (int t = 0; t < NT; ++t) {
        const int cur = (t & 1) << 15;          // halfword offset of current buf
        const int nxt = cur ^ 32768;
        const unsigned short* pA0 = &lds[cur];
        const unsigned short* pB0 = &lds[cur + 8192];
        const unsigned short* pA1 = &lds[cur + 16384];
        const unsigned short* pB1 = &lds[cur + 24576];
        const int k1 = (t + 1) << 6;
        const bool pf = (t < NT - 1);

        bf16x8 a[8], b[4];

        // ---- phase 1: ds_read ks0 (12 x b128); stage next A-ks0 ----
#pragma unroll
        for (int i = 0; i < 8; ++i)
            a[i] = *(const bf16x8*)&pA0[(wm * 128 + i * 16) * 32 + lro];
#pragma unroll
        for (int j = 0; j < 4; ++j)
            b[j] = *(const bf16x8*)&pB0[(wn * 64 + j * 16) * 32 + lro];
        if (pf) STAGE(nxt, 0, Ab, k1);
        __builtin_amdgcn_s_barrier();
        __builtin_amdgcn_s_setprio(1);
#pragma unroll
        for (int i = 0; i < 8; ++i) {
            acc[i][0] = MFMA(a[i], b[0], acc[i][0]);
            acc[i][1] = MFMA(a[i], b[1], acc[i][1]);
        }
        __builtin_amdgcn_s_setprio(0);
        __builtin_amdgcn_s_barrier();

        // ---- phase 2: stage next B-ks0; MFMA ks0 n2,3; counted wait ----
        if (pf) STAGE(nxt, 1, Wb, k1);
        __builtin_amdgcn_s_barrier();
        __builtin_amdgcn_s_setprio(1);
#pragma unroll
        for (int i = 0; i < 8; ++i) {
            acc[i][2] = MFMA(a[i], b[2], acc[i][2]);
            acc[i][3] = MFMA(a[i], b[3], acc[i][3]);
        }
        __builtin_amdgcn_s_setprio(0);
        __builtin_amdgcn_sched_barrier(0);
        if (pf) asm volatile("s_waitcnt vmcnt(4)" ::: "memory");   // ks1 of t landed
        else    asm volatile("s_waitcnt vmcnt(0)" ::: "memory");   // final drain
        __builtin_amdgcn_s_barrier();
        __builtin_amdgcn_sched_barrier(0);

        // ---- phase 3: ds_read ks1 (12 x b128); stage next A-ks1 ----
#pragma unroll
        for (int i = 0; i < 8; ++i)
            a[i] = *(const bf16x8*)&pA1[(wm * 128 + i * 16) * 32 + lro];
#pragma unroll
        for (int j = 0; j < 4; ++j)
            b[j] = *(const bf16x8*)&pB1[(wn * 64 + j * 16) * 32 + lro];
        if (pf) STAGE(nxt, 2, Ab, k1 + 32);
        __builtin_amdgcn_s_barrier();
        __builtin_amdgcn_s_setprio(1);
#pragma unroll
        for (int i = 0; i < 8; ++i) {
            acc[i][0] = MFMA(a[i], b[0], acc[i][0]);
            acc[i][1] = MFMA(a[i], b[1], acc[i][1]);
        }
        __builtin_amdgcn_s_setprio(0);
        __builtin_amdgcn_s_barrier();

        // ---- phase 4: stage next B-ks1; MFMA ks1 n2,3; counted wait ----
        if (pf) STAGE(nxt, 3, Wb, k1 + 32);
        __builtin_amdgcn_s_barrier();
        __builtin_amdgcn_s_setprio(1);
#pragma unroll
        for (int i = 0; i < 8; ++i) {
            acc[i][2] = MFMA(a[i], b[2], acc[i][2]);
            acc[i][3] = MFMA(a[i], b[3], acc[i][3]);
        }
        __builtin_amdgcn_s_setprio(0);
        if (pf) {
            __builtin_amdgcn_sched_barrier(0);
            asm volatile("s_waitcnt vmcnt(4)" ::: "memory");       // ks0 of t+1 landed
            __builtin_amdgcn_s_barrier();
            __builtin_amdgcn_sched_barrier(0);
        }
    }
#undef STAGE

    // ---- epilogue: D mapping col=lane&15, row=(lane>>4)*4+reg (m89-verified) ----
    const long rowA0 = (long)bm * 256;
    const int  colB0 = bn * 256;
#pragma unroll
    for (int j = 0; j < 4; ++j) {
        const int ncol = colB0 + wn * 64 + j * 16 + l15;
        const float s = scale[ncol];
#pragma unroll
        for (int i = 0; i < 8; ++i) {
            float* cp = C + (rowA0 + wm * 128 + i * 16 + c16 * 4) * (long)NDIM + ncol;
#pragma unroll
            for (int r = 0; r < 4; ++r)
                cp[(long)r * NDIM] = acc[i][j][r] * s;
        }
    }
}

// ---------------- safety fallback (no workspace needed, fp32, slow) ----------------

__global__ __launch_bounds__(256)
void fallback_kernel(const float* __restrict__ x, const int* __restrict__ q,
                     const float* __restrict__ scale, const int* __restrict__ zp,
                     float* __restrict__ out) {
    __shared__ float sA[64][17];
    __shared__ float sB[64][17];
    const int bn = (int)blockIdx.x % (NDIM / 64);
    const int bm = (int)blockIdx.x / (NDIM / 64);
    const int t  = threadIdx.x;
    const int tx = t & 15, ty = t >> 4;
    const long rowA = (long)bm * 64, rowB = (long)bn * 64;
    float acc[4][4] = {};
    for (int k0 = 0; k0 < KDIM; k0 += 16) {
#pragma unroll
        for (int i = 0; i < 4; ++i) {
            const int e = t + i * 256;
            const int r = e >> 4, c = e & 15;
            sA[r][c] = x[(rowA + r) * KDIM + k0 + c];
            const int o = (int)rowB + r;
            sB[r][c] = (float)(q[(long)o * KDIM + k0 + c] - zp[o]) * scale[o];
        }
        __syncthreads();
#pragma unroll
        for (int kk = 0; kk < 16; ++kk) {
            float a[4], b[4];
#pragma unroll
            for (int i = 0; i < 4; ++i) a[i] = sA[ty * 4 + i][kk];
#pragma unroll
            for (int j = 0; j < 4; ++j) b[j] = sB[tx * 4 + j][kk];
#pragma unroll
            for (int i = 0; i < 4; ++i)
#pragma unroll
                for (int j = 0; j < 4; ++j) acc[i][j] += a[i] * b[j];
        }
        __syncthreads();
    }
#pragma unroll
    for (int i = 0; i < 4; ++i) {
        const long r = rowA + ty * 4 + i;
#pragma unroll
        for (int j = 0; j < 4; ++j)
            out[r * NDIM + rowB + tx * 4 + j] = acc[i][j];
    }
}

// ---------------- launch ----------------

extern "C" void kernel_launch(void* const* d_in, const int* in_sizes, int n_in,
                              void* d_out, int out_size, void* d_ws, size_t ws_size,
                              hipStream_t stream) {
    const float* x     = (const float*)d_in[0];
    const int*   qw    = (const int*)d_in[1];
    const float* scale = (const float*)d_in[2];
    const int*   zp    = (const int*)d_in[3];
    float*       out   = (float*)d_out;

    const size_t needA = (size_t)MDIM * KDIM * sizeof(unsigned short);  // 64 MiB
    const size_t needW = (size_t)NDIM * KDIM * sizeof(unsigned short);  // 128 MiB

    if (ws_size >= needA + needW) {
        unsigned short* xb = (unsigned short*)d_ws;
        unsigned short* wb = xb + (size_t)MDIM * KDIM;
        convert_x_kernel<<<2048, 256, 0, stream>>>(x, xb);
        convert_w_kernel<<<4096, 256, 0, stream>>>(qw, zp, wb);
        (void)hipFuncSetAttribute((const void*)gemm8_kernel,
                                  hipFuncAttributeMaxDynamicSharedMemorySize, 131072);
        gemm8_kernel<<<(MDIM / 256) * (NDIM / 256), 512, 131072, stream>>>(xb, wb, scale, out);
    } else {
        fallback_kernel<<<(MDIM / 64) * (NDIM / 64), 256, 0, stream>>>(x, qw, scale, zp, out);
    }
}

// Round 3
// 1120.965 us; speedup vs baseline: 1.4934x; 1.1290x over previous
//
#include <hip/hip_runtime.h>
#include <stdint.h>

#define MDIM 8192
#define NDIM 16384
#define KDIM 4096
#define NT   64          // K-tiles of BK=64

typedef __attribute__((ext_vector_type(8))) short bf16x8;
typedef __attribute__((ext_vector_type(4))) float f32x4;

__device__ __forceinline__ unsigned short f2bf(float f) {
    unsigned int u = __float_as_uint(f);
    u += 0x7FFFu + ((u >> 16) & 1u);   // RNE; inputs finite/normal
    return (unsigned short)(u >> 16);
}

__device__ __forceinline__ void gload_lds16(const void* g, void* l) {
    __builtin_amdgcn_global_load_lds(
        (const __attribute__((address_space(1))) void*)g,
        (__attribute__((address_space(3))) void*)l,
        16, 0, 0);
}

__device__ __forceinline__ f32x4 MFMA(bf16x8 a, bf16x8 b, f32x4 c) {
    return __builtin_amdgcn_mfma_f32_16x16x32_bf16(a, b, c, 0, 0, 0);
}

// ---------------- conversion kernels ----------------

__global__ __launch_bounds__(256)
void convert_x_kernel(const float* __restrict__ x, unsigned short* __restrict__ xb) {
    const long n8 = (long)MDIM * KDIM / 8;
    long i = (long)blockIdx.x * blockDim.x + threadIdx.x;
    const long stride = (long)gridDim.x * blockDim.x;
    for (; i < n8; i += stride) {
        const float4* p = (const float4*)(x + i * 8);
        float4 a = p[0];
        float4 b = p[1];
        union { unsigned short u[8]; uint4 v; } r;
        r.u[0] = f2bf(a.x); r.u[1] = f2bf(a.y); r.u[2] = f2bf(a.z); r.u[3] = f2bf(a.w);
        r.u[4] = f2bf(b.x); r.u[5] = f2bf(b.y); r.u[6] = f2bf(b.z); r.u[7] = f2bf(b.w);
        *(uint4*)(xb + i * 8) = r.v;
    }
}

__global__ __launch_bounds__(256)
void convert_w_kernel(const int* __restrict__ q, const int* __restrict__ zp,
                      unsigned short* __restrict__ wb) {
    const long n8 = (long)NDIM * KDIM / 8;
    long i = (long)blockIdx.x * blockDim.x + threadIdx.x;
    const long stride = (long)gridDim.x * blockDim.x;
    for (; i < n8; i += stride) {
        const long e = i * 8;
        const int o = (int)(e >> 12);          // KDIM = 4096
        const int z = zp[o];
        const int4* p = (const int4*)(q + e);
        int4 a = p[0];
        int4 b = p[1];
        union { unsigned short u[8]; uint4 v; } r;
        r.u[0] = f2bf((float)(a.x - z)); r.u[1] = f2bf((float)(a.y - z));
        r.u[2] = f2bf((float)(a.z - z)); r.u[3] = f2bf((float)(a.w - z));
        r.u[4] = f2bf((float)(b.x - z)); r.u[5] = f2bf((float)(b.y - z));
        r.u[6] = f2bf((float)(b.z - z)); r.u[7] = f2bf((float)(b.w - z));
        *(uint4*)(wb + e) = r.v;
    }
}

// ---------------- 256x256 8-wave 4-phase MFMA GEMM (T1+T2+T3+T4+T5) ----------------
// C[m,n] = scale[n] * sum_k A[m,k] * W[n,k]
// LDS: 2 bufs x 4 planes x 8192 halfwords = 128 KiB.
//   plane 0: A k-slice 0 (256 rows x 32 k)   plane 1: B k-slice 0
//   plane 2: A k-slice 1                     plane 3: B k-slice 1
// Chunk XOR-swizzle (2-way = free) via pre-swizzled GLOBAL source, linear
// global_load_lds dest. Counted vmcnt(4) waits, setprio around MFMA.
//
// Block mapping (locality): round r = 256 concurrent blocks (1/CU) covers
// ALL 32 A-panels x 8 B-panels -> A (64 MB) L3-resident across the whole
// kernel; per-round fresh B = 16 MB; round set (A+B+out) ~147 MB < L3.
// Blocks sharing an A-panel sit on ONE XCD (i%8 == bm%8) -> A L2-served.

__global__ __launch_bounds__(512, 2)
void gemm8_kernel(const unsigned short* __restrict__ A,
                  const unsigned short* __restrict__ W,
                  const float* __restrict__ scale,
                  float* __restrict__ C) {
    extern __shared__ unsigned short lds[];   // 65536 halfwords

    const int wg = (int)blockIdx.x;
    const int rr = wg >> 8;                   // round 0..7
    const int ii = wg & 255;
    const int bm = ii & 31;                   // 0..31 (all A-panels each round)
    const int bn = rr * 8 + (ii >> 5);        // 0..63 (8 fresh B-panels/round)

    const int tid  = threadIdx.x;
    const int lane = tid & 63;
    const int wid  = tid >> 6;
    const int wm   = wid >> 2;        // 0..1  (128 rows each)
    const int wn   = wid & 3;         // 0..3  (64 cols each)
    const int l15  = lane & 15;
    const int c16  = lane >> 4;

    // swizzled read offset within a plane (halfwords): row*32 + chunk*8
    const int lro = l15 * 32 + ((c16 ^ ((l15 >> 1) & 3)) << 3);

    // staging: thread covers plane slots s0 = tid, s1 = 512+tid
    // slot s holds (row = s>>2, logical chunk c = (s&3) ^ ((s>>3)&3))
    const int s0 = tid, s1 = 512 + tid;
    const int soff0 = (s0 >> 2) * KDIM + (((s0 & 3) ^ ((s0 >> 3) & 3)) << 3);
    const int soff1 = (s1 >> 2) * KDIM + (((s1 & 3) ^ ((s1 >> 3) & 3)) << 3);
    const int d0 = s0 * 8, d1 = s1 * 8;   // halfword offsets in plane (16B/lane, linear)

    const unsigned short* Ab = A + (long)bm * 256 * KDIM;
    const unsigned short* Wb = W + (long)bn * 256 * KDIM;

#define STAGE(buf, p, base, kofs)                                                   \
    do {                                                                            \
        gload_lds16((base) + soff0 + (kofs), &lds[(buf) + (p) * 8192 + d0]);        \
        gload_lds16((base) + soff1 + (kofs), &lds[(buf) + (p) * 8192 + d1]);        \
    } while (0)

    f32x4 acc[8][4];
#pragma unroll
    for (int i = 0; i < 8; ++i)
#pragma unroll
        for (int j = 0; j < 4; ++j) acc[i][j] = (f32x4){0.f, 0.f, 0.f, 0.f};

    // prologue: K-tile 0 (8 loads); wait planes 0,1
    STAGE(0, 0, Ab, 0);
    STAGE(0, 1, Wb, 0);
    STAGE(0, 2, Ab, 32);
    STAGE(0, 3, Wb, 32);
    asm volatile("s_waitcnt vmcnt(4)" ::: "memory");
    __builtin_amdgcn_s_barrier();
    __builtin_amdgcn_sched_barrier(0);

    for (int t = 0; t < NT; ++t) {
        const int cur = (t & 1) << 15;          // halfword offset of current buf
        const int nxt = cur ^ 32768;
        const unsigned short* pA0 = &lds[cur];
        const unsigned short* pB0 = &lds[cur + 8192];
        const unsigned short* pA1 = &lds[cur + 16384];
        const unsigned short* pB1 = &lds[cur + 24576];
        const int k1 = (t + 1) << 6;
        const bool pf = (t < NT - 1);

        bf16x8 a[8], b[4];

        // ---- phase 1: ds_read ks0 (12 x b128); stage next A-ks0 ----
#pragma unroll
        for (int i = 0; i < 8; ++i)
            a[i] = *(const bf16x8*)&pA0[(wm * 128 + i * 16) * 32 + lro];
#pragma unroll
        for (int j = 0; j < 4; ++j)
            b[j] = *(const bf16x8*)&pB0[(wn * 64 + j * 16) * 32 + lro];
        if (pf) STAGE(nxt, 0, Ab, k1);
        __builtin_amdgcn_s_barrier();
        __builtin_amdgcn_s_setprio(1);
#pragma unroll
        for (int i = 0; i < 8; ++i) {
            acc[i][0] = MFMA(a[i], b[0], acc[i][0]);
            acc[i][1] = MFMA(a[i], b[1], acc[i][1]);
        }
        __builtin_amdgcn_s_setprio(0);
        __builtin_amdgcn_s_barrier();

        // ---- phase 2: stage next B-ks0; MFMA ks0 n2,3; counted wait ----
        if (pf) STAGE(nxt, 1, Wb, k1);
        __builtin_amdgcn_s_barrier();
        __builtin_amdgcn_s_setprio(1);
#pragma unroll
        for (int i = 0; i < 8; ++i) {
            acc[i][2] = MFMA(a[i], b[2], acc[i][2]);
            acc[i][3] = MFMA(a[i], b[3], acc[i][3]);
        }
        __builtin_amdgcn_s_setprio(0);
        __builtin_amdgcn_sched_barrier(0);
        if (pf) asm volatile("s_waitcnt vmcnt(4)" ::: "memory");   // ks1 of t landed
        else    asm volatile("s_waitcnt vmcnt(0)" ::: "memory");   // final drain
        __builtin_amdgcn_s_barrier();
        __builtin_amdgcn_sched_barrier(0);

        // ---- phase 3: ds_read ks1 (12 x b128); stage next A-ks1 ----
#pragma unroll
        for (int i = 0; i < 8; ++i)
            a[i] = *(const bf16x8*)&pA1[(wm * 128 + i * 16) * 32 + lro];
#pragma unroll
        for (int j = 0; j < 4; ++j)
            b[j] = *(const bf16x8*)&pB1[(wn * 64 + j * 16) * 32 + lro];
        if (pf) STAGE(nxt, 2, Ab, k1 + 32);
        __builtin_amdgcn_s_barrier();
        __builtin_amdgcn_s_setprio(1);
#pragma unroll
        for (int i = 0; i < 8; ++i) {
            acc[i][0] = MFMA(a[i], b[0], acc[i][0]);
            acc[i][1] = MFMA(a[i], b[1], acc[i][1]);
        }
        __builtin_amdgcn_s_setprio(0);
        __builtin_amdgcn_s_barrier();

        // ---- phase 4: stage next B-ks1; MFMA ks1 n2,3; counted wait ----
        if (pf) STAGE(nxt, 3, Wb, k1 + 32);
        __builtin_amdgcn_s_barrier();
        __builtin_amdgcn_s_setprio(1);
#pragma unroll
        for (int i = 0; i < 8; ++i) {
            acc[i][2] = MFMA(a[i], b[2], acc[i][2]);
            acc[i][3] = MFMA(a[i], b[3], acc[i][3]);
        }
        __builtin_amdgcn_s_setprio(0);
        if (pf) {
            __builtin_amdgcn_sched_barrier(0);
            asm volatile("s_waitcnt vmcnt(4)" ::: "memory");       // ks0 of t+1 landed
            __builtin_amdgcn_s_barrier();
            __builtin_amdgcn_sched_barrier(0);
        }
    }
#undef STAGE

    // ---- epilogue: D mapping col=lane&15, row=(lane>>4)*4+reg (m89-verified) ----
    const long rowA0 = (long)bm * 256;
    const int  colB0 = bn * 256;
#pragma unroll
    for (int j = 0; j < 4; ++j) {
        const int ncol = colB0 + wn * 64 + j * 16 + l15;
        const float s = scale[ncol];
#pragma unroll
        for (int i = 0; i < 8; ++i) {
            float* cp = C + (rowA0 + wm * 128 + i * 16 + c16 * 4) * (long)NDIM + ncol;
#pragma unroll
            for (int r = 0; r < 4; ++r)
                cp[(long)r * NDIM] = acc[i][j][r] * s;
        }
    }
}

// ---------------- safety fallback (no workspace needed, fp32, slow) ----------------

__global__ __launch_bounds__(256)
void fallback_kernel(const float* __restrict__ x, const int* __restrict__ q,
                     const float* __restrict__ scale, const int* __restrict__ zp,
                     float* __restrict__ out) {
    __shared__ float sA[64][17];
    __shared__ float sB[64][17];
    const int bn = (int)blockIdx.x % (NDIM / 64);
    const int bm = (int)blockIdx.x / (NDIM / 64);
    const int t  = threadIdx.x;
    const int tx = t & 15, ty = t >> 4;
    const long rowA = (long)bm * 64, rowB = (long)bn * 64;
    float acc[4][4] = {};
    for (int k0 = 0; k0 < KDIM; k0 += 16) {
#pragma unroll
        for (int i = 0; i < 4; ++i) {
            const int e = t + i * 256;
            const int r = e >> 4, c = e & 15;
            sA[r][c] = x[(rowA + r) * KDIM + k0 + c];
            const int o = (int)rowB + r;
            sB[r][c] = (float)(q[(long)o * KDIM + k0 + c] - zp[o]) * scale[o];
        }
        __syncthreads();
#pragma unroll
        for (int kk = 0; kk < 16; ++kk) {
            float a[4], b[4];
#pragma unroll
            for (int i = 0; i < 4; ++i) a[i] = sA[ty * 4 + i][kk];
#pragma unroll
            for (int j = 0; j < 4; ++j) b[j] = sB[tx * 4 + j][kk];
#pragma unroll
            for (int i = 0; i < 4; ++i)
#pragma unroll
                for (int j = 0; j < 4; ++j) acc[i][j] += a[i] * b[j];
        }
        __syncthreads();
    }
#pragma unroll
    for (int i = 0; i < 4; ++i) {
        const long r = rowA + ty * 4 + i;
#pragma unroll
        for (int j = 0; j < 4; ++j)
            out[r * NDIM + rowB + tx * 4 + j] = acc[i][j];
    }
}

// ---------------- launch ----------------

extern "C" void kernel_launch(void* const* d_in, const int* in_sizes, int n_in,
                              void* d_out, int out_size, void* d_ws, size_t ws_size,
                              hipStream_t stream) {
    const float* x     = (const float*)d_in[0];
    const int*   qw    = (const int*)d_in[1];
    const float* scale = (const float*)d_in[2];
    const int*   zp    = (const int*)d_in[3];
    float*       out   = (float*)d_out;

    const size_t needA = (size_t)MDIM * KDIM * sizeof(unsigned short);  // 64 MiB
    const size_t needW = (size_t)NDIM * KDIM * sizeof(unsigned short);  // 128 MiB

    if (ws_size >= needA + needW) {
        unsigned short* xb = (unsigned short*)d_ws;
        unsigned short* wb = xb + (size_t)MDIM * KDIM;
        convert_x_kernel<<<2048, 256, 0, stream>>>(x, xb);
        convert_w_kernel<<<4096, 256, 0, stream>>>(qw, zp, wb);
        (void)hipFuncSetAttribute((const void*)gemm8_kernel,
                                  hipFuncAttributeMaxDynamicSharedMemorySize, 131072);
        gemm8_kernel<<<(MDIM / 256) * (NDIM / 256), 512, 131072, stream>>>(xb, wb, scale, out);
    } else {
        fallback_kernel<<<(MDIM / 64) * (NDIM / 64), 256, 0, stream>>>(x, qw, scale, zp, out);
    }
}

// Round 4
// 1113.072 us; speedup vs baseline: 1.5040x; 1.0071x over previous
//
#include <hip/hip_runtime.h>
#include <stdint.h>

#define MDIM 8192
#define NDIM 16384
#define KDIM 4096
#define NT   64          // K-tiles of BK=64

typedef __attribute__((ext_vector_type(8))) short bf16x8;
typedef __attribute__((ext_vector_type(4))) float f32x4;

__device__ __forceinline__ unsigned short f2bf(float f) {
    unsigned int u = __float_as_uint(f);
    u += 0x7FFFu + ((u >> 16) & 1u);   // RNE; inputs finite/normal
    return (unsigned short)(u >> 16);
}

__device__ __forceinline__ void gload_lds16(const void* g, void* l) {
    __builtin_amdgcn_global_load_lds(
        (const __attribute__((address_space(1))) void*)g,
        (__attribute__((address_space(3))) void*)l,
        16, 0, 0);
}

__device__ __forceinline__ f32x4 MFMA(bf16x8 a, bf16x8 b, f32x4 c) {
    return __builtin_amdgcn_mfma_f32_16x16x32_bf16(a, b, c, 0, 0, 0);
}

// ---------------- conversion kernels ----------------

__global__ __launch_bounds__(256)
void convert_x_kernel(const float* __restrict__ x, unsigned short* __restrict__ xb) {
    const long n8 = (long)MDIM * KDIM / 8;
    long i = (long)blockIdx.x * blockDim.x + threadIdx.x;
    const long stride = (long)gridDim.x * blockDim.x;
    for (; i < n8; i += stride) {
        const float4* p = (const float4*)(x + i * 8);
        float4 a = p[0];
        float4 b = p[1];
        union { unsigned short u[8]; uint4 v; } r;
        r.u[0] = f2bf(a.x); r.u[1] = f2bf(a.y); r.u[2] = f2bf(a.z); r.u[3] = f2bf(a.w);
        r.u[4] = f2bf(b.x); r.u[5] = f2bf(b.y); r.u[6] = f2bf(b.z); r.u[7] = f2bf(b.w);
        *(uint4*)(xb + i * 8) = r.v;
    }
}

__global__ __launch_bounds__(256)
void convert_w_kernel(const int* __restrict__ q, const int* __restrict__ zp,
                      unsigned short* __restrict__ wb) {
    const long n8 = (long)NDIM * KDIM / 8;
    long i = (long)blockIdx.x * blockDim.x + threadIdx.x;
    const long stride = (long)gridDim.x * blockDim.x;
    for (; i < n8; i += stride) {
        const long e = i * 8;
        const int o = (int)(e >> 12);          // KDIM = 4096
        const int z = zp[o];
        const int4* p = (const int4*)(q + e);
        int4 a = p[0];
        int4 b = p[1];
        union { unsigned short u[8]; uint4 v; } r;
        r.u[0] = f2bf((float)(a.x - z)); r.u[1] = f2bf((float)(a.y - z));
        r.u[2] = f2bf((float)(a.z - z)); r.u[3] = f2bf((float)(a.w - z));
        r.u[4] = f2bf((float)(b.x - z)); r.u[5] = f2bf((float)(b.y - z));
        r.u[6] = f2bf((float)(b.z - z)); r.u[7] = f2bf((float)(b.w - z));
        *(uint4*)(wb + e) = r.v;
    }
}

// ---------------- 256x256 8-wave software-pipelined MFMA GEMM ----------------
// C[m,n] = scale[n] * sum_k A[m,k] * W[n,k]
// LDS: 2 bufs x 4 planes x 8192 halfwords = 128 KiB.
//   plane 0: A ks0 (256r x 32k)  plane 1: B ks0  plane 2: A ks1  plane 3: B ks1
// Chunk XOR-swizzle via pre-swizzled GLOBAL source, linear gload_lds dest.
//
// Pipeline (per K-tile, 4 phases x 16 MFMA): each phase ds_reads the NEXT
// phase's frags (balanced 4/8/4/8 b128) into the alternate register set, so
// every read has a full MFMA phase of latency cover; 1 barrier/phase;
// vmcnt(2) only before phi1/phi3 (each staged plane waits >=2 phases after
// issue). Stage order per tile: phi0->nxtA0, phi1->nxtB0, phi2->nxtA1,
// phi3->nxtB1 (2 gloads each).
//
// Block mapping (locality): round r = 256 concurrent blocks covers ALL 32
// A-panels x 8 B-panels; A (64 MB) L3-resident, fresh B 16 MB/round;
// A-panel sharers sit on one XCD (ii%8 == bm%8).

__global__ __launch_bounds__(512, 2)
void gemm8_kernel(const unsigned short* __restrict__ A,
                  const unsigned short* __restrict__ W,
                  const float* __restrict__ scale,
                  float* __restrict__ C) {
    extern __shared__ unsigned short lds[];   // 65536 halfwords

    const int wg = (int)blockIdx.x;
    const int rr = wg >> 8;                   // round 0..7
    const int ii = wg & 255;
    const int bm = ii & 31;                   // 0..31 (all A-panels each round)
    const int bn = rr * 8 + (ii >> 5);        // 0..63 (8 fresh B-panels/round)

    const int tid  = threadIdx.x;
    const int lane = tid & 63;
    const int wid  = tid >> 6;
    const int wm   = wid >> 2;        // 0..1  (128 rows each)
    const int wn   = wid & 3;         // 0..3  (64 cols each)
    const int l15  = lane & 15;
    const int c16  = lane >> 4;

    // swizzled read offset within a plane (halfwords): row*32 + chunk*8
    const int lro = l15 * 32 + ((c16 ^ ((l15 >> 1) & 3)) << 3);

    // staging: thread covers plane slots s0 = tid, s1 = 512+tid
    const int s0 = tid, s1 = 512 + tid;
    const int soff0 = (s0 >> 2) * KDIM + (((s0 & 3) ^ ((s0 >> 3) & 3)) << 3);
    const int soff1 = (s1 >> 2) * KDIM + (((s1 & 3) ^ ((s1 >> 3) & 3)) << 3);
    const int d0 = s0 * 8, d1 = s1 * 8;

    const unsigned short* Ab = A + (long)bm * 256 * KDIM;
    const unsigned short* Wb = W + (long)bn * 256 * KDIM;

#define STAGE(buf, p, base, kofs)                                                   \
    do {                                                                            \
        gload_lds16((base) + soff0 + (kofs), &lds[(buf) + (p) * 8192 + d0]);        \
        gload_lds16((base) + soff1 + (kofs), &lds[(buf) + (p) * 8192 + d1]);        \
    } while (0)

#define RD_A(DST, PL, RB)                                                           \
    _Pragma("unroll")                                                               \
    for (int i_ = 0; i_ < 4; ++i_)                                                  \
        DST[i_] = *(const bf16x8*)&(PL)[((wm * 128 + ((RB) + i_) * 16) << 5) + lro];

#define RD_B(DST, PL)                                                               \
    _Pragma("unroll")                                                               \
    for (int j_ = 0; j_ < 4; ++j_)                                                  \
        DST[j_] = *(const bf16x8*)&(PL)[((wn * 64 + j_ * 16) << 5) + lro];

#define MFMA_HALF(IH, ASET, BSET)                                                   \
    _Pragma("unroll")                                                               \
    for (int i_ = 0; i_ < 4; ++i_)                                                  \
        _Pragma("unroll")                                                           \
        for (int j_ = 0; j_ < 4; ++j_)                                              \
            acc[(IH) * 4 + i_][j_] = MFMA(ASET[i_], BSET[j_], acc[(IH) * 4 + i_][j_]);

    f32x4 acc[8][4];
#pragma unroll
    for (int i = 0; i < 8; ++i)
#pragma unroll
        for (int j = 0; j < 4; ++j) acc[i][j] = (f32x4){0.f, 0.f, 0.f, 0.f};

    bf16x8 aA[4], aB[4], bA[4], bB[4];

    // prologue: stage K-tile 0 (planes in phi order), wait planes 0,1; pre-read phi0 frags
    STAGE(0, 0, Ab, 0);
    STAGE(0, 1, Wb, 0);
    STAGE(0, 2, Ab, 32);
    STAGE(0, 3, Wb, 32);
    asm volatile("s_waitcnt vmcnt(4)" ::: "memory");
    __builtin_amdgcn_s_barrier();
    RD_A(aA, &lds[0], 0);
    RD_B(bA, &lds[8192]);

    for (int t = 0; t < NT; ++t) {
        const int cur = (t & 1) << 15;
        const int nxt = cur ^ 32768;
        const unsigned short* cA0 = &lds[cur];
        const unsigned short* cA1 = &lds[cur + 16384];
        const unsigned short* cB1 = &lds[cur + 24576];
        const unsigned short* nA0 = &lds[nxt];
        const unsigned short* nB0 = &lds[nxt + 8192];
        const int k1 = (t + 1) << 6;
        const bool pf = (t < NT - 1);

        // ---- phi0: read aB<-curA0[4..7]; stage nxtA0; MFMA aA x bA -> acc[0..3] ----
        __builtin_amdgcn_s_barrier();
        RD_A(aB, cA0, 4);
        if (pf) STAGE(nxt, 0, Ab, k1);
        __builtin_amdgcn_sched_barrier(0);
        __builtin_amdgcn_s_setprio(1);
        MFMA_HALF(0, aA, bA);
        __builtin_amdgcn_s_setprio(0);

        // ---- phi1: wait curA1/curB1 landed; read aA<-curA1[0..3], bB<-curB1;
        //           stage nxtB0; MFMA aB x bA -> acc[4..7] ----
        if (pf) asm volatile("s_waitcnt vmcnt(2)" ::: "memory");
        else    asm volatile("s_waitcnt vmcnt(0)" ::: "memory");
        __builtin_amdgcn_s_barrier();
        RD_A(aA, cA1, 0);
        RD_B(bB, cB1);
        if (pf) STAGE(nxt, 1, Wb, k1);
        __builtin_amdgcn_sched_barrier(0);
        __builtin_amdgcn_s_setprio(1);
        MFMA_HALF(1, aB, bA);
        __builtin_amdgcn_s_setprio(0);

        // ---- phi2: read aB<-curA1[4..7]; stage nxtA1; MFMA aA x bB -> acc[0..3] ----
        __builtin_amdgcn_s_barrier();
        RD_A(aB, cA1, 4);
        if (pf) STAGE(nxt, 2, Ab, k1 + 32);
        __builtin_amdgcn_sched_barrier(0);
        __builtin_amdgcn_s_setprio(1);
        MFMA_HALF(0, aA, bB);
        __builtin_amdgcn_s_setprio(0);

        // ---- phi3: wait nxtA0/nxtB0 landed; read aA<-nxtA0[0..3], bA<-nxtB0;
        //           stage nxtB1; MFMA aB x bB -> acc[4..7] ----
        if (pf) {
            asm volatile("s_waitcnt vmcnt(2)" ::: "memory");
            __builtin_amdgcn_s_barrier();
            RD_A(aA, nA0, 0);
            RD_B(bA, nB0);
            STAGE(nxt, 3, Wb, k1 + 32);
        } else {
            __builtin_amdgcn_s_barrier();
        }
        __builtin_amdgcn_sched_barrier(0);
        __builtin_amdgcn_s_setprio(1);
        MFMA_HALF(1, aB, bB);
        __builtin_amdgcn_s_setprio(0);
    }
#undef STAGE
#undef RD_A
#undef RD_B
#undef MFMA_HALF

    // ---- epilogue: D mapping col=lane&15, row=(lane>>4)*4+reg (m89-verified) ----
    const long rowA0 = (long)bm * 256;
    const int  colB0 = bn * 256;
#pragma unroll
    for (int j = 0; j < 4; ++j) {
        const int ncol = colB0 + wn * 64 + j * 16 + l15;
        const float s = scale[ncol];
#pragma unroll
        for (int i = 0; i < 8; ++i) {
            float* cp = C + (rowA0 + wm * 128 + i * 16 + c16 * 4) * (long)NDIM + ncol;
#pragma unroll
            for (int r = 0; r < 4; ++r)
                cp[(long)r * NDIM] = acc[i][j][r] * s;
        }
    }
}

// ---------------- safety fallback (no workspace needed, fp32, slow) ----------------

__global__ __launch_bounds__(256)
void fallback_kernel(const float* __restrict__ x, const int* __restrict__ q,
                     const float* __restrict__ scale, const int* __restrict__ zp,
                     float* __restrict__ out) {
    __shared__ float sA[64][17];
    __shared__ float sB[64][17];
    const int bn = (int)blockIdx.x % (NDIM / 64);
    const int bm = (int)blockIdx.x / (NDIM / 64);
    const int t  = threadIdx.x;
    const int tx = t & 15, ty = t >> 4;
    const long rowA = (long)bm * 64, rowB = (long)bn * 64;
    float acc[4][4] = {};
    for (int k0 = 0; k0 < KDIM; k0 += 16) {
#pragma unroll
        for (int i = 0; i < 4; ++i) {
            const int e = t + i * 256;
            const int r = e >> 4, c = e & 15;
            sA[r][c] = x[(rowA + r) * KDIM + k0 + c];
            const int o = (int)rowB + r;
            sB[r][c] = (float)(q[(long)o * KDIM + k0 + c] - zp[o]) * scale[o];
        }
        __syncthreads();
#pragma unroll
        for (int kk = 0; kk < 16; ++kk) {
            float a[4], b[4];
#pragma unroll
            for (int i = 0; i < 4; ++i) a[i] = sA[ty * 4 + i][kk];
#pragma unroll
            for (int j = 0; j < 4; ++j) b[j] = sB[tx * 4 + j][kk];
#pragma unroll
            for (int i = 0; i < 4; ++i)
#pragma unroll
                for (int j = 0; j < 4; ++j) acc[i][j] += a[i] * b[j];
        }
        __syncthreads();
    }
#pragma unroll
    for (int i = 0; i < 4; ++i) {
        const long r = rowA + ty * 4 + i;
#pragma unroll
        for (int j = 0; j < 4; ++j)
            out[r * NDIM + rowB + tx * 4 + j] = acc[i][j];
    }
}

// ---------------- launch ----------------

extern "C" void kernel_launch(void* const* d_in, const int* in_sizes, int n_in,
                              void* d_out, int out_size, void* d_ws, size_t ws_size,
                              hipStream_t stream) {
    const float* x     = (const float*)d_in[0];
    const int*   qw    = (const int*)d_in[1];
    const float* scale = (const float*)d_in[2];
    const int*   zp    = (const int*)d_in[3];
    float*       out   = (float*)d_out;

    const size_t needA = (size_t)MDIM * KDIM * sizeof(unsigned short);  // 64 MiB
    const size_t needW = (size_t)NDIM * KDIM * sizeof(unsigned short);  // 128 MiB

    if (ws_size >= needA + needW) {
        unsigned short* xb = (unsigned short*)d_ws;
        unsigned short* wb = xb + (size_t)MDIM * KDIM;
        convert_x_kernel<<<2048, 256, 0, stream>>>(x, xb);
        convert_w_kernel<<<4096, 256, 0, stream>>>(qw, zp, wb);
        (void)hipFuncSetAttribute((const void*)gemm8_kernel,
                                  hipFuncAttributeMaxDynamicSharedMemorySize, 131072);
        gemm8_kernel<<<(MDIM / 256) * (NDIM / 256), 512, 131072, stream>>>(xb, wb, scale, out);
    } else {
        fallback_kernel<<<(MDIM / 64) * (NDIM / 64), 256, 0, stream>>>(x, qw, scale, zp, out);
    }
}